// Round 1
// baseline (85.744 us; speedup 1.0000x reference)
//
#include <hip/hip_runtime.h>
#include <hip/hip_bf16.h>

typedef __attribute__((ext_vector_type(4))) float f32x4;
typedef __attribute__((ext_vector_type(8))) short short8;

#define B_ 16
#define C_ 64
#define H_ 128
#define W_ 128
#define Z_ 128
#define IDXN (C_*C_*9)    // 36864 weight elements per sample
#define NT 18             // K=576 -> 18 MFMA k-steps of 32

__device__ __forceinline__ unsigned short f2bf(float f) {
  __hip_bfloat16 h = __float2bfloat16(f);
  return *reinterpret_cast<unsigned short*>(&h);
}

// ---------------- kernel 1: weight generation, pre-swizzled to MFMA A-fragment layout
// k ordering: k = (kh*3+kw)*64 + ci  (so 8 consecutive k = 8 consecutive ci)
// storage: wfrag[b][t][m][lane][j]  (t = k>>5, m = co>>4, lane = (co&15)|(((k&31)>>3)<<4), j = k&7)
__global__ __launch_bounds__(256) void wgen_k(
    const float* __restrict__ z, const float* __restrict__ gw,
    const float* __restrict__ gb, unsigned short* __restrict__ wfrag) {
  __shared__ __align__(16) float zs[B_*Z_];   // 8 KB
  int t = threadIdx.x;
#pragma unroll
  for (int i = 0; i < 8; ++i) zs[i*256 + t] = z[i*256 + t];
  __syncthreads();
  int idx = blockIdx.x*256 + t;               // 0..36863, coalesced gen_w reads
  int kw = idx % 3, r1 = idx/3;
  int kh = r1 % 3, r2 = r1/3;
  int ci = r2 & 63, co = r2 >> 6;
  float acc[B_];
  float bv = gb[idx];
#pragma unroll
  for (int b = 0; b < B_; ++b) acc[b] = bv;
  for (int z0 = 0; z0 < Z_; z0 += 4) {
    float g0 = gw[(z0+0)*IDXN + idx];
    float g1 = gw[(z0+1)*IDXN + idx];
    float g2 = gw[(z0+2)*IDXN + idx];
    float g3 = gw[(z0+3)*IDXN + idx];
#pragma unroll
    for (int b = 0; b < B_; ++b) {
      f32x4 zv = *reinterpret_cast<const f32x4*>(&zs[b*Z_ + z0]);
      acc[b] = fmaf(zv[0], g0, fmaf(zv[1], g1, fmaf(zv[2], g2, fmaf(zv[3], g3, acc[b]))));
    }
  }
  int k = (kh*3 + kw)*C_ + ci;
  int ts = k >> 5, kin = k & 31;
  int lane = (co & 15) | ((kin >> 3) << 4);
  int j = kin & 7, m = co >> 4;
  int base = ((ts*4 + m)*64 + lane)*8 + j;
#pragma unroll
  for (int b = 0; b < B_; ++b)
    wfrag[b*(NT*4*64*8) + base] = f2bf(acc[b]);
}

// ---------------- kernel 2: x [b][ci][h][w] fp32 -> xT [b][h][w][ci] bf16
__global__ __launch_bounds__(256) void xpose_k(
    const float* __restrict__ x, unsigned short* __restrict__ xT) {
  int p = blockIdx.x;               // 16*128 blocks: (b, h)
  int b = p >> 7, h = p & 127;
  int t = threadIdx.x;
  int g = t & 7, wl = t >> 3;       // g: ci-chunk (8 ci), wl: w lane
  const float* xb = x + (b*C_*H_ + h)*W_;          // + ci*H_*W_ + w
  unsigned short* dst = xT + ((b*H_ + h)*W_)*C_;   // + w*C_ + ci
#pragma unroll
  for (int wi = 0; wi < 4; ++wi) {
    int w = wi*32 + wl;
    unsigned int u[4];
#pragma unroll
    for (int jj = 0; jj < 4; ++jj) {
      float f0 = xb[(g*8 + 2*jj + 0)*(H_*W_) + w];
      float f1 = xb[(g*8 + 2*jj + 1)*(H_*W_) + w];
      u[jj] = (unsigned int)f2bf(f0) | ((unsigned int)f2bf(f1) << 16);
    }
    uint4 val; val.x = u[0]; val.y = u[1]; val.z = u[2]; val.w = u[3];
    *reinterpret_cast<uint4*>(dst + w*C_ + g*8) = val;   // coalesced 16B stores
  }
}

// ---------------- kernel 3: per-sample conv as MFMA implicit GEMM
// block: (sample b, output rows h0,h0+1). 4 waves; wave v -> row phr=v>>1, pixel half pw0=(v&1)*64.
// LDS: xs[4 rows][130 cols][64 ci] bf16, XOR-swizzled 16B chunks (chunk ^= col&7).
__global__ __launch_bounds__(256) void conv_k(
    const unsigned short* __restrict__ xT,
    const unsigned short* __restrict__ wfrag,
    float* __restrict__ out) {
  __shared__ __align__(16) unsigned char xs[4*130*128];   // 66560 B
  int orig = blockIdx.x;
  int blk = (orig & 7)*128 + (orig >> 3);   // bijective XCD swizzle: 1024 = 8*128
  int b = blk >> 6;
  int h0 = (blk & 63)*2;
  int tid = threadIdx.x;
  int v = tid >> 6, lane = tid & 63;

  // ---- stage 4 halo rows (h0-1..h0+2), wave v handles row v
  {
    int hh = h0 - 1 + v;
    bool hv = (hh >= 0) & (hh < H_);
    const unsigned short* xrow = xT + ((b*H_ + hh)*W_)*C_;
#pragma unroll
    for (int it = 0; it < 17; ++it) {
      int di = it*64 + lane;                 // 130 cols * 8 chunks = 1040
      if (di < 1040) {
        int col = di >> 3, ch = di & 7;
        uint4 val; val.x = 0; val.y = 0; val.z = 0; val.w = 0;
        if (hv && col >= 1 && col <= 128)
          val = *reinterpret_cast<const uint4*>(xrow + (col-1)*C_ + ch*8);
        int dstb = (v*130 + col)*128 + (((ch ^ col) & 7) << 4);
        *reinterpret_cast<uint4*>(&xs[dstb]) = val;
      }
    }
  }
  __syncthreads();

  int l15 = lane & 15, lhi = lane >> 4;
  int phr = v >> 1, pw0 = (v & 1)*64;
  f32x4 acc[4][4];
#pragma unroll
  for (int m = 0; m < 4; ++m)
#pragma unroll
    for (int n = 0; n < 4; ++n)
      acc[m][n] = (f32x4){0.f, 0.f, 0.f, 0.f};

  const unsigned short* wb = wfrag + b*(NT*4*64*8);
#pragma unroll
  for (int t = 0; t < NT; ++t) {
    int kk = t >> 1, kh = kk/3, kw = kk%3, half = t & 1;
    short8 a[4];
#pragma unroll
    for (int m = 0; m < 4; ++m)            // coalesced 1KiB L2-hot fragment loads
      a[m] = *reinterpret_cast<const short8*>(wb + ((t*4 + m)*64 + lane)*8);
    int chunk = half*4 + lhi;              // ci0>>3
    short8 bf[4];
#pragma unroll
    for (int n = 0; n < 4; ++n) {
      int col = pw0 + n*16 + l15 + kw;     // padded col = pw + kw, in [0,129]
      int addr = ((phr + kh)*130 + col)*128 + (((chunk ^ col) & 7) << 4);
      bf[n] = *reinterpret_cast<const short8*>(&xs[addr]);
    }
#pragma unroll
    for (int m = 0; m < 4; ++m)
#pragma unroll
      for (int n = 0; n < 4; ++n)
        acc[m][n] = __builtin_amdgcn_mfma_f32_16x16x32_bf16(a[m], bf[n], acc[m][n], 0, 0, 0);
  }

  // ---- epilogue: D col=lane&15 (pixel), row=(lane>>4)*4+i (co)
  int ph = h0 + phr;
  float* ob = out + (b*C_*H_ + ph)*W_;
#pragma unroll
  for (int m = 0; m < 4; ++m)
#pragma unroll
    for (int n = 0; n < 4; ++n)
#pragma unroll
      for (int i = 0; i < 4; ++i) {
        int co = m*16 + lhi*4 + i;
        ob[co*(H_*W_) + pw0 + n*16 + l15] = acc[m][n][i];
      }
}

__global__ void sentinel_k(float* out, int n) {
  int i = blockIdx.x*256 + threadIdx.x;
  if (i < n) out[i] = 1.0e6f;
}

extern "C" void kernel_launch(void* const* d_in, const int* in_sizes, int n_in,
                              void* d_out, int out_size, void* d_ws, size_t ws_size,
                              hipStream_t stream) {
  const float* x  = (const float*)d_in[0];
  const float* z  = (const float*)d_in[1];
  const float* gw = (const float*)d_in[2];
  const float* gb = (const float*)d_in[3];
  float* out = (float*)d_out;

  size_t wfrag_elems = (size_t)B_*IDXN;                   // bf16 elems
  size_t xT_elems    = (size_t)B_*H_*W_*C_;               // bf16 elems
  size_t need = (wfrag_elems + xT_elems)*sizeof(unsigned short);
  if (ws_size < need) {   // unmistakable sentinel if workspace is too small
    sentinel_k<<<(out_size + 255)/256, 256, 0, stream>>>(out, out_size);
    return;
  }
  unsigned short* wfrag = (unsigned short*)d_ws;
  unsigned short* xT    = wfrag + wfrag_elems;

  wgen_k <<<IDXN/256, 256, 0, stream>>>(z, gw, gb, wfrag);
  xpose_k<<<B_*H_,    256, 0, stream>>>(x, xT);
  conv_k <<<B_*(H_/2),256, 0, stream>>>(xT, wfrag, out);
}

// Round 2
// 75.501 us; speedup vs baseline: 1.1357x; 1.1357x over previous
//
#include <hip/hip_runtime.h>
#include <hip/hip_bf16.h>

typedef __attribute__((ext_vector_type(4))) float f32x4;
typedef __attribute__((ext_vector_type(8))) short short8;

#define B_ 16
#define C_ 64
#define H_ 128
#define W_ 128
#define Z_ 128
#define IDXN (C_*C_*9)    // 36864 weight elements per sample
#define NT 18             // K=576 -> 18 MFMA k-steps of 32

#define AS_GLOBAL(p) ((const __attribute__((address_space(1))) void*)(p))
#define AS_LDS(p)    ((__attribute__((address_space(3))) void*)(p))

__device__ __forceinline__ unsigned short f2bf(float f) {
  __hip_bfloat16 h = __float2bfloat16(f);
  return *reinterpret_cast<unsigned short*>(&h);
}

// ---------------- kernel 1: weight generation, pre-swizzled to MFMA A-fragment layout
// k ordering: k = (kh*3+kw)*64 + ci; storage wfrag[b][t][m][lane][j]
__global__ __launch_bounds__(128) void wgen_k(
    const float* __restrict__ z, const float* __restrict__ gw,
    const float* __restrict__ gb, unsigned short* __restrict__ wfrag) {
  __shared__ __align__(16) float zs[B_*Z_];   // 8 KB
  int t = threadIdx.x;
#pragma unroll
  for (int i = 0; i < 16; ++i) zs[i*128 + t] = z[i*128 + t];
  __syncthreads();
  int idx = blockIdx.x*128 + t;               // 0..36863, coalesced gen_w reads
  int kw = idx % 3, r1 = idx/3;
  int kh = r1 % 3, r2 = r1/3;
  int ci = r2 & 63, co = r2 >> 6;
  float acc[B_];
  float bv = gb[idx];
#pragma unroll
  for (int b = 0; b < B_; ++b) acc[b] = bv;
  for (int z0 = 0; z0 < Z_; z0 += 4) {
    float g0 = gw[(z0+0)*IDXN + idx];
    float g1 = gw[(z0+1)*IDXN + idx];
    float g2 = gw[(z0+2)*IDXN + idx];
    float g3 = gw[(z0+3)*IDXN + idx];
#pragma unroll
    for (int b = 0; b < B_; ++b) {
      f32x4 zv = *reinterpret_cast<const f32x4*>(&zs[b*Z_ + z0]);
      acc[b] = fmaf(zv[0], g0, fmaf(zv[1], g1, fmaf(zv[2], g2, fmaf(zv[3], g3, acc[b]))));
    }
  }
  int k = (kh*3 + kw)*C_ + ci;
  int ts = k >> 5, kin = k & 31;
  int lane = (co & 15) | ((kin >> 3) << 4);
  int j = kin & 7, m = co >> 6 ? 0 : co >> 4; // co<64 always; m = co>>4
  m = co >> 4;
  int base = ((ts*4 + m)*64 + lane)*8 + j;
#pragma unroll
  for (int b = 0; b < B_; ++b)
    wfrag[b*(NT*4*64*8) + base] = f2bf(acc[b]);
}

// ---------------- kernel 2: x [b][ci][h][w] fp32 -> xTs [b][h][w][swizzled ci-chunks] bf16
// chunk c of (w, ci=c*8..c*8+7) stored at slot c ^ ((w+1)&7)  (conv LDS swizzle baked in)
__global__ __launch_bounds__(256) void xpose_k(
    const float* __restrict__ x, unsigned short* __restrict__ xTs) {
  __shared__ __align__(16) unsigned short lt[C_*132];   // stride 132 shorts = 264 B
  int p = blockIdx.x;               // (b, h)
  int b = p >> 7, h = p & 127;
  int t = threadIdx.x;
  const float* xb = x + ((size_t)b*C_*H_ + h)*W_;      // + ci*H*W + w

  // phase 1: coalesced float4 reads along w, bf16-pack, write LDS [ci][w]
  int wq = t & 31, ci0 = t >> 5;    // wq: w-quad, ci0: 0..7
#pragma unroll
  for (int p8 = 0; p8 < 8; ++p8) {
    int ci = ci0 + p8*8;
    f32x4 v = *reinterpret_cast<const f32x4*>(&xb[(size_t)ci*(H_*W_) + wq*4]);
    unsigned int u0 = (unsigned int)f2bf(v[0]) | ((unsigned int)f2bf(v[1]) << 16);
    unsigned int u1 = (unsigned int)f2bf(v[2]) | ((unsigned int)f2bf(v[3]) << 16);
    uint2 val; val.x = u0; val.y = u1;
    *reinterpret_cast<uint2*>(&lt[ci*132 + wq*4]) = val;
  }
  __syncthreads();

  // phase 2: read transposed (b32 = two w at fixed ci), pack uint4 of 8 ci, store swizzled
  int ci8 = t & 7, wp0 = t >> 3;    // ci8: chunk, wp0: 0..31 (w-pair index)
  unsigned short* dst = xTs + ((size_t)(b*H_ + h)*W_)*C_;
#pragma unroll
  for (int wi = 0; wi < 2; ++wi) {
    int wp = wp0 + wi*32;           // w-pair 0..63 -> w = 2*wp, 2*wp+1
    unsigned int q[8];
#pragma unroll
    for (int j = 0; j < 8; ++j)
      q[j] = *reinterpret_cast<const unsigned int*>(&lt[(ci8*8 + j)*132 + wp*2]);
    uint4 o0, o1;
    unsigned short* s0 = reinterpret_cast<unsigned short*>(&o0);
    unsigned short* s1 = reinterpret_cast<unsigned short*>(&o1);
#pragma unroll
    for (int j = 0; j < 8; ++j) {
      s0[j] = (unsigned short)(q[j] & 0xffffu);
      s1[j] = (unsigned short)(q[j] >> 16);
    }
    int w0 = 2*wp, w1 = 2*wp + 1;
    int sl0 = ci8 ^ ((w0 + 1) & 7);
    int sl1 = ci8 ^ ((w1 + 1) & 7);
    *reinterpret_cast<uint4*>(dst + (size_t)w0*C_ + sl0*8) = o0;
    *reinterpret_cast<uint4*>(dst + (size_t)w1*C_ + sl1*8) = o1;
  }
}

// ---------------- kernel 3: per-sample conv as MFMA implicit GEMM
// LDS: xs[4 rows][130 cols][8 chunk-slots][16B]; content slot s of col = chunk s^(col&7)
__global__ __launch_bounds__(256) void conv_k(
    const unsigned short* __restrict__ xTs,
    const unsigned short* __restrict__ wfrag,
    float* __restrict__ out) {
  __shared__ __align__(16) unsigned char xs[4*130*128];   // 66560 B
  int orig = blockIdx.x;
  int blk = (orig & 7)*128 + (orig >> 3);   // bijective XCD swizzle: 1024 = 8*128
  int b = blk >> 6;
  int h0 = (blk & 63)*2;
  int tid = threadIdx.x;
  int v = tid >> 6, lane = tid & 63;

  // ---- stage 4 halo rows (h0-1..h0+2) via global_load_lds, wave v -> row v
  {
    int hh = h0 - 1 + v;
    bool hv = (hh >= 0) & (hh < H_);
    unsigned char* ldsrow = xs + v*(130*128);
    if (hv) {
      // pre-zero pad cols 0 and 129 (slots 0..7 and 1032..1039)
      if (lane < 16) {
        int s = (lane < 8) ? lane : (1024 + lane);
        uint4 zv; zv.x = 0; zv.y = 0; zv.z = 0; zv.w = 0;
        *reinterpret_cast<uint4*>(ldsrow + s*16) = zv;
      }
      const unsigned char* xrow = reinterpret_cast<const unsigned char*>(
          xTs + ((size_t)(b*H_ + hh)*W_)*C_);
#pragma unroll
      for (int it = 0; it < 16; ++it) {
        // slots 8 + it*64 + lane  <-  src chunk (it*64 + lane), 16 B each
        __builtin_amdgcn_global_load_lds(
            AS_GLOBAL(xrow + ((size_t)(it*64))*16 + (size_t)lane*16),
            AS_LDS(ldsrow + (8 + it*64)*16), 16, 0, 0);
      }
    } else {
      uint4 zv; zv.x = 0; zv.y = 0; zv.z = 0; zv.w = 0;
#pragma unroll
      for (int it = 0; it < 17; ++it) {
        int di = it*64 + lane;
        if (di < 1040) *reinterpret_cast<uint4*>(ldsrow + di*16) = zv;
      }
    }
  }
  __syncthreads();

  int l15 = lane & 15, lhi = lane >> 4;
  int phr = v >> 1, pw0 = (v & 1)*64;
  f32x4 acc[4][4];
#pragma unroll
  for (int m = 0; m < 4; ++m)
#pragma unroll
    for (int n = 0; n < 4; ++n)
      acc[m][n] = (f32x4){0.f, 0.f, 0.f, 0.f};

  const unsigned short* wb = wfrag + (size_t)b*(NT*4*64*8);
#pragma unroll
  for (int t = 0; t < NT; ++t) {
    int kk = t >> 1, kh = kk/3, kw = kk%3, half = t & 1;
    short8 a[4];
#pragma unroll
    for (int m = 0; m < 4; ++m)            // coalesced 1KiB L2-hot fragment loads
      a[m] = *reinterpret_cast<const short8*>(wb + ((t*4 + m)*64 + lane)*8);
    int chunk = half*4 + lhi;              // ci0>>3
    short8 bf[4];
#pragma unroll
    for (int n = 0; n < 4; ++n) {
      int col = pw0 + n*16 + l15 + kw;     // padded col = pix + kw, in [0,129]
      int addr = ((phr + kh)*130 + col)*128 + (((chunk ^ col) & 7) << 4);
      bf[n] = *reinterpret_cast<const short8*>(&xs[addr]);
    }
#pragma unroll
    for (int m = 0; m < 4; ++m)
#pragma unroll
      for (int n = 0; n < 4; ++n)
        acc[m][n] = __builtin_amdgcn_mfma_f32_16x16x32_bf16(a[m], bf[n], acc[m][n], 0, 0, 0);
  }

  // ---- epilogue: D col=lane&15 (pixel), row=(lane>>4)*4+i (co)
  int ph = h0 + phr;
  float* ob = out + ((size_t)b*C_*H_ + ph)*W_;
#pragma unroll
  for (int m = 0; m < 4; ++m)
#pragma unroll
    for (int n = 0; n < 4; ++n)
#pragma unroll
      for (int i = 0; i < 4; ++i) {
        int co = m*16 + lhi*4 + i;
        ob[(size_t)co*(H_*W_) + pw0 + n*16 + l15] = acc[m][n][i];
      }
}

__global__ void sentinel_k(float* out, int n) {
  int i = blockIdx.x*256 + threadIdx.x;
  if (i < n) out[i] = 1.0e6f;
}

extern "C" void kernel_launch(void* const* d_in, const int* in_sizes, int n_in,
                              void* d_out, int out_size, void* d_ws, size_t ws_size,
                              hipStream_t stream) {
  const float* x  = (const float*)d_in[0];
  const float* z  = (const float*)d_in[1];
  const float* gw = (const float*)d_in[2];
  const float* gb = (const float*)d_in[3];
  float* out = (float*)d_out;

  size_t wfrag_elems = (size_t)B_*IDXN;                   // bf16 elems
  size_t xT_elems    = (size_t)B_*H_*W_*C_;               // bf16 elems
  size_t need = (wfrag_elems + xT_elems)*sizeof(unsigned short);
  if (ws_size < need) {
    sentinel_k<<<(out_size + 255)/256, 256, 0, stream>>>(out, out_size);
    return;
  }
  unsigned short* wfrag = (unsigned short*)d_ws;
  unsigned short* xTs   = wfrag + wfrag_elems;

  wgen_k <<<IDXN/128, 128, 0, stream>>>(z, gw, gb, wfrag);
  xpose_k<<<B_*H_,    256, 0, stream>>>(x, xTs);
  conv_k <<<B_*(H_/2),256, 0, stream>>>(xTs, wfrag, out);
}

// Round 3
// 62.264 us; speedup vs baseline: 1.3771x; 1.2126x over previous
//
#include <hip/hip_runtime.h>
#include <hip/hip_bf16.h>

typedef __attribute__((ext_vector_type(4))) float f32x4;
typedef __attribute__((ext_vector_type(8))) short short8;

#define B_ 16
#define C_ 64
#define H_ 128
#define W_ 128
#define Z_ 128
#define IDXN (C_*C_*9)    // 36864 weight elements per sample
#define NT 18             // K=576 -> 18 MFMA k-steps of 32

#define AS_GLOBAL(p) ((const __attribute__((address_space(1))) void*)(p))
#define AS_LDS(p)    ((__attribute__((address_space(3))) void*)(p))

__device__ __forceinline__ unsigned short f2bf(float f) {
  __hip_bfloat16 h = __float2bfloat16(f);
  return *reinterpret_cast<unsigned short*>(&h);
}

// ---------------- kernel 1: weight generation, pre-swizzled to MFMA fragment layout
// wave = b-group of 4 samples, lanes = 2 idx streams -> FMA:LDS = 8:1, 1152 waves
__global__ __launch_bounds__(256) void wgen_k(
    const float* __restrict__ z, const float* __restrict__ gw,
    const float* __restrict__ gb, unsigned short* __restrict__ wfrag) {
  __shared__ __align__(16) float zs[B_*Z_];   // 8 KB
  int t = threadIdx.x;
#pragma unroll
  for (int i = 0; i < 8; ++i) zs[i*256 + t] = z[i*256 + t];
  __syncthreads();
  int lane = t & 63, bg = t >> 6;
  int b0 = bg*4;
  int idx0 = blockIdx.x*128 + lane;           // stream 0: idx0, stream 1: idx0+64
  float acc[4][2];
  float bv0 = gb[idx0], bv1 = gb[idx0 + 64];
#pragma unroll
  for (int bi = 0; bi < 4; ++bi) { acc[bi][0] = bv0; acc[bi][1] = bv1; }

  for (int z0 = 0; z0 < Z_; z0 += 4) {
    float ga[4], gbv[4];
#pragma unroll
    for (int zi = 0; zi < 4; ++zi) {
      ga[zi]  = gw[(size_t)(z0+zi)*IDXN + idx0];
      gbv[zi] = gw[(size_t)(z0+zi)*IDXN + idx0 + 64];
    }
#pragma unroll
    for (int bi = 0; bi < 4; ++bi) {
      f32x4 zq = *reinterpret_cast<const f32x4*>(&zs[(b0+bi)*Z_ + z0]);
      acc[bi][0] = fmaf(zq[0], ga[0], fmaf(zq[1], ga[1], fmaf(zq[2], ga[2], fmaf(zq[3], ga[3], acc[bi][0]))));
      acc[bi][1] = fmaf(zq[0], gbv[0], fmaf(zq[1], gbv[1], fmaf(zq[2], gbv[2], fmaf(zq[3], gbv[3], acc[bi][1]))));
    }
  }
#pragma unroll
  for (int ni = 0; ni < 2; ++ni) {
    int idx = idx0 + ni*64;
    int kw = idx % 3, r1 = idx/3;
    int kh = r1 % 3, r2 = r1/3;
    int ci = r2 & 63, co = r2 >> 6;
    int k = (kh*3 + kw)*C_ + ci;
    int ts = k >> 5, kin = k & 31;
    int lm = (co & 15) | ((kin >> 3) << 4);
    int j = kin & 7, m = co >> 4;
    int base = ((ts*4 + m)*64 + lm)*8 + j;
#pragma unroll
    for (int bi = 0; bi < 4; ++bi)
      wfrag[(size_t)(b0+bi)*(NT*4*64*8) + base] = f2bf(acc[bi][ni]);
  }
}

// ---------------- kernel 2: x [b][ci][h][w] fp32 -> xTs [b][h][w][swizzled ci-chunks] bf16
// chunk c of (w, ci=c*8..c*8+7) stored at slot c ^ ((w+1)&7)  (conv LDS swizzle baked in)
__global__ __launch_bounds__(256) void xpose_k(
    const float* __restrict__ x, unsigned short* __restrict__ xTs) {
  __shared__ __align__(16) unsigned short lt[C_*134];   // stride 134 shorts (bank-spread)
  int p = blockIdx.x;               // (b, h)
  int b = p >> 7, h = p & 127;
  int t = threadIdx.x;
  const float* xb = x + ((size_t)b*C_*H_ + h)*W_;      // + ci*H*W + w

  // phase 1: coalesced float4 reads along w, bf16-pack, write LDS [ci][w]
  int wq = t & 31, ci0 = t >> 5;    // wq: w-quad, ci0: 0..7
#pragma unroll
  for (int p8 = 0; p8 < 8; ++p8) {
    int ci = ci0 + p8*8;
    f32x4 v = *reinterpret_cast<const f32x4*>(&xb[(size_t)ci*(H_*W_) + wq*4]);
    unsigned int u0 = (unsigned int)f2bf(v[0]) | ((unsigned int)f2bf(v[1]) << 16);
    unsigned int u1 = (unsigned int)f2bf(v[2]) | ((unsigned int)f2bf(v[3]) << 16);
    uint2 val; val.x = u0; val.y = u1;
    *reinterpret_cast<uint2*>(&lt[ci*134 + wq*4]) = val;
  }
  __syncthreads();

  // phase 2: read transposed (b32 = two w at fixed ci), pack uint4 of 8 ci, store swizzled
  int ci8 = t & 7, wp0 = t >> 3;    // ci8: chunk, wp0: 0..31 (w-pair index)
  unsigned short* dst = xTs + ((size_t)(b*H_ + h)*W_)*C_;
#pragma unroll
  for (int wi = 0; wi < 2; ++wi) {
    int wp = wp0 + wi*32;           // w-pair 0..63 -> w = 2*wp, 2*wp+1
    unsigned int q[8];
#pragma unroll
    for (int j = 0; j < 8; ++j)
      q[j] = *reinterpret_cast<const unsigned int*>(&lt[(ci8*8 + j)*134 + wp*2]);
    uint4 o0, o1;
    unsigned short* s0 = reinterpret_cast<unsigned short*>(&o0);
    unsigned short* s1 = reinterpret_cast<unsigned short*>(&o1);
#pragma unroll
    for (int j = 0; j < 8; ++j) {
      s0[j] = (unsigned short)(q[j] & 0xffffu);
      s1[j] = (unsigned short)(q[j] >> 16);
    }
    int w0 = 2*wp, w1 = 2*wp + 1;
    int sl0 = ci8 ^ ((w0 + 1) & 7);
    int sl1 = ci8 ^ ((w1 + 1) & 7);
    *reinterpret_cast<uint4*>(dst + (size_t)w0*C_ + sl0*8) = o0;
    *reinterpret_cast<uint4*>(dst + (size_t)w1*C_ + sl1*8) = o1;
  }
}

// ---------------- kernel 3: per-sample conv as MFMA implicit GEMM
// A = x (row = pixel), B = wfrag (col = co)  ->  D[row=pixel][col=co], f32x4 stores
// LDS: xs[4 rows][130 cols][8 chunk-slots][16B]; content slot s of col = chunk s^(col&7)
__global__ __launch_bounds__(256) void conv_k(
    const unsigned short* __restrict__ xTs,
    const unsigned short* __restrict__ wfrag,
    float* __restrict__ out) {
  __shared__ __align__(16) unsigned char xs[4*130*128];   // 66560 B
  int orig = blockIdx.x;
  int blk = (orig & 7)*128 + (orig >> 3);   // bijective XCD swizzle: 1024 = 8*128
  int b = blk >> 6;
  int h0 = (blk & 63)*2;
  int tid = threadIdx.x;
  int v = tid >> 6, lane = tid & 63;

  // ---- stage 4 halo rows (h0-1..h0+2) via global_load_lds, wave v -> row v
  {
    int hh = h0 - 1 + v;
    bool hv = (hh >= 0) & (hh < H_);
    unsigned char* ldsrow = xs + v*(130*128);
    if (hv) {
      if (lane < 16) {   // pre-zero pad cols 0 and 129
        int s = (lane < 8) ? lane : (1024 + lane);
        uint4 zv; zv.x = 0; zv.y = 0; zv.z = 0; zv.w = 0;
        *reinterpret_cast<uint4*>(ldsrow + s*16) = zv;
      }
      const unsigned char* xrow = reinterpret_cast<const unsigned char*>(
          xTs + ((size_t)(b*H_ + hh)*W_)*C_);
#pragma unroll
      for (int it = 0; it < 16; ++it) {
        __builtin_amdgcn_global_load_lds(
            AS_GLOBAL(xrow + ((size_t)(it*64))*16 + (size_t)lane*16),
            AS_LDS(ldsrow + (8 + it*64)*16), 16, 0, 0);
      }
    } else {
      uint4 zv; zv.x = 0; zv.y = 0; zv.z = 0; zv.w = 0;
#pragma unroll
      for (int it = 0; it < 17; ++it) {
        int di = it*64 + lane;
        if (di < 1040) *reinterpret_cast<uint4*>(ldsrow + di*16) = zv;
      }
    }
  }
  __syncthreads();

  int l15 = lane & 15, lhi = lane >> 4;
  int phr = v >> 1, pw0 = (v & 1)*64;
  f32x4 acc[4][4];   // [pixel tile][co tile]
#pragma unroll
  for (int mp = 0; mp < 4; ++mp)
#pragma unroll
    for (int nc = 0; nc < 4; ++nc)
      acc[mp][nc] = (f32x4){0.f, 0.f, 0.f, 0.f};

  const unsigned short* wb = wfrag + (size_t)b*(NT*4*64*8);
#pragma unroll
  for (int t = 0; t < NT; ++t) {
    int kk = t >> 1, kh = kk/3, kw = kk%3, half = t & 1;
    short8 wf[4];
#pragma unroll
    for (int nc = 0; nc < 4; ++nc)         // B operand: weights (L1/L2-hot, 1 KiB/instr)
      wf[nc] = *reinterpret_cast<const short8*>(wb + ((t*4 + nc)*64 + lane)*8);
    int chunk = half*4 + lhi;              // ci0>>3
    short8 xa[4];
#pragma unroll
    for (int mp = 0; mp < 4; ++mp) {       // A operand: pixels from LDS
      int col = pw0 + mp*16 + l15 + kw;    // padded col = pix + kw, in [0,129]
      int addr = ((phr + kh)*130 + col)*128 + (((chunk ^ col) & 7) << 4);
      xa[mp] = *reinterpret_cast<const short8*>(&xs[addr]);
    }
#pragma unroll
    for (int mp = 0; mp < 4; ++mp)
#pragma unroll
      for (int nc = 0; nc < 4; ++nc)
        acc[mp][nc] = __builtin_amdgcn_mfma_f32_16x16x32_bf16(xa[mp], wf[nc], acc[mp][nc], 0, 0, 0);
  }

  // ---- epilogue: D row=(lane>>4)*4+i -> pixel (contiguous!), col=lane&15 -> co
  int ph = h0 + phr;
#pragma unroll
  for (int nc = 0; nc < 4; ++nc) {
    int co = nc*16 + l15;
    float* op = out + (((size_t)b*C_ + co)*H_ + ph)*W_;
#pragma unroll
    for (int mp = 0; mp < 4; ++mp) {
      int pix = pw0 + mp*16 + lhi*4;
      *reinterpret_cast<f32x4*>(op + pix) = acc[mp][nc];
    }
  }
}

__global__ void sentinel_k(float* out, int n) {
  int i = blockIdx.x*256 + threadIdx.x;
  if (i < n) out[i] = 1.0e6f;
}

extern "C" void kernel_launch(void* const* d_in, const int* in_sizes, int n_in,
                              void* d_out, int out_size, void* d_ws, size_t ws_size,
                              hipStream_t stream) {
  const float* x  = (const float*)d_in[0];
  const float* z  = (const float*)d_in[1];
  const float* gw = (const float*)d_in[2];
  const float* gb = (const float*)d_in[3];
  float* out = (float*)d_out;

  size_t wfrag_elems = (size_t)B_*IDXN;                   // bf16 elems
  size_t xT_elems    = (size_t)B_*H_*W_*C_;               // bf16 elems
  size_t need = (wfrag_elems + xT_elems)*sizeof(unsigned short);
  if (ws_size < need) {
    sentinel_k<<<(out_size + 255)/256, 256, 0, stream>>>(out, out_size);
    return;
  }
  unsigned short* wfrag = (unsigned short*)d_ws;
  unsigned short* xTs   = wfrag + wfrag_elems;

  wgen_k <<<IDXN/128, 256, 0, stream>>>(z, gw, gb, wfrag);
  xpose_k<<<B_*H_,    256, 0, stream>>>(x, xTs);
  conv_k <<<B_*(H_/2),256, 0, stream>>>(xTs, wfrag, out);
}

// Round 4
// 50.452 us; speedup vs baseline: 1.6995x; 1.2341x over previous
//
#include <hip/hip_runtime.h>
#include <hip/hip_bf16.h>

typedef __attribute__((ext_vector_type(4))) float f32x4;
typedef __attribute__((ext_vector_type(8))) short short8;

#define B_ 16
#define C_ 64
#define H_ 128
#define W_ 128
#define Z_ 128
#define IDXN (C_*C_*9)    // 36864 weight elements per sample
#define NT 18             // K=576 -> 18 MFMA k-steps of 32

__device__ __forceinline__ unsigned short f2bf(float f) {
  __hip_bfloat16 h = __float2bfloat16(f);
  return *reinterpret_cast<unsigned short*>(&h);
}

// ---------------- kernel 1: weight generation, pre-swizzled to MFMA fragment layout
// wave = b-group of 4 samples, lanes = 2 idx streams -> FMA:LDS = 8:1, 1152 waves
__global__ __launch_bounds__(256) void wgen_k(
    const float* __restrict__ z, const float* __restrict__ gw,
    const float* __restrict__ gb, unsigned short* __restrict__ wfrag) {
  __shared__ __align__(16) float zs[B_*Z_];   // 8 KB
  int t = threadIdx.x;
#pragma unroll
  for (int i = 0; i < 8; ++i) zs[i*256 + t] = z[i*256 + t];
  __syncthreads();
  int lane = t & 63, bg = t >> 6;
  int b0 = bg*4;
  int idx0 = blockIdx.x*128 + lane;           // stream 0: idx0, stream 1: idx0+64
  float acc[4][2];
  float bv0 = gb[idx0], bv1 = gb[idx0 + 64];
#pragma unroll
  for (int bi = 0; bi < 4; ++bi) { acc[bi][0] = bv0; acc[bi][1] = bv1; }

  for (int z0 = 0; z0 < Z_; z0 += 4) {
    float ga[4], gbv[4];
#pragma unroll
    for (int zi = 0; zi < 4; ++zi) {
      ga[zi]  = gw[(size_t)(z0+zi)*IDXN + idx0];
      gbv[zi] = gw[(size_t)(z0+zi)*IDXN + idx0 + 64];
    }
#pragma unroll
    for (int bi = 0; bi < 4; ++bi) {
      f32x4 zq = *reinterpret_cast<const f32x4*>(&zs[(b0+bi)*Z_ + z0]);
      acc[bi][0] = fmaf(zq[0], ga[0], fmaf(zq[1], ga[1], fmaf(zq[2], ga[2], fmaf(zq[3], ga[3], acc[bi][0]))));
      acc[bi][1] = fmaf(zq[0], gbv[0], fmaf(zq[1], gbv[1], fmaf(zq[2], gbv[2], fmaf(zq[3], gbv[3], acc[bi][1]))));
    }
  }
#pragma unroll
  for (int ni = 0; ni < 2; ++ni) {
    int idx = idx0 + ni*64;
    int kw = idx % 3, r1 = idx/3;
    int kh = r1 % 3, r2 = r1/3;
    int ci = r2 & 63, co = r2 >> 6;
    int k = (kh*3 + kw)*C_ + ci;
    int ts = k >> 5, kin = k & 31;
    int lm = (co & 15) | ((kin >> 3) << 4);
    int j = kin & 7, m = co >> 4;
    int base = ((ts*4 + m)*64 + lm)*8 + j;
#pragma unroll
    for (int bi = 0; bi < 4; ++bi)
      wfrag[(size_t)(b0+bi)*(NT*4*64*8) + base] = f2bf(acc[bi][ni]);
  }
}

// ---------------- kernel 2 (fused): per-sample conv as MFMA implicit GEMM,
// transpose+bf16-convert of x folded into LDS staging (no xT intermediate).
// A = x (row = pixel), B = wfrag (col = co)  ->  D[row=pixel][col=co], f32x4 stores
// LDS: xs[4 rows][130 cols][8 chunk-slots][16B]; content: slot s at col holds chunk s^(col&7)
__global__ __launch_bounds__(256) void conv_k(
    const float* __restrict__ x,
    const unsigned short* __restrict__ wfrag,
    float* __restrict__ out) {
  __shared__ __align__(16) unsigned char xs[4*130*128];   // 66560 B -> 2 blocks/CU
  int orig = blockIdx.x;
  int blk = (orig & 7)*128 + (orig >> 3);   // bijective XCD swizzle: 1024 = 8*128
  int b = blk >> 6;
  int h0 = (blk & 63)*2;
  int tid = threadIdx.x;
  int v = tid >> 6, lane = tid & 63;

  // ---- stage 4 halo rows (h0-1..h0+2); wave v -> row v. fp32 load + bf16 pack + swizzled ds_write
  {
    int hh = h0 - 1 + v;
    bool hv = (hh >= 0) & (hh < H_);
    unsigned char* ldsrow = xs + v*(130*128);
    if (hv) {
      if (lane < 16) {   // zero pad cols 0 and 129 (slots 0..7, 1032..1039)
        int s = (lane < 8) ? lane : (1024 + lane - 8 + 8);   // 1032..1039
        uint4 zv; zv.x = 0; zv.y = 0; zv.z = 0; zv.w = 0;
        *reinterpret_cast<uint4*>(ldsrow + s*16) = zv;
      }
      const float* xrow = x + (((size_t)b*C_)*H_ + hh)*W_;   // + ci*(H_*W_) + w
      int w0 = 2*lane, col0 = w0 + 1, col1 = w0 + 2;
      int g = lane >> 3;                                     // lane-group chunk rotation
#pragma unroll
      for (int c8 = 0; c8 < 8; ++c8) {
        int chunk = (c8 + g) & 7;
        float2 v2[8];
#pragma unroll
        for (int j = 0; j < 8; ++j)
          v2[j] = *reinterpret_cast<const float2*>(xrow + (size_t)(chunk*8 + j)*(H_*W_) + w0);
        uint4 o0, o1;
        unsigned short* s0 = reinterpret_cast<unsigned short*>(&o0);
        unsigned short* s1 = reinterpret_cast<unsigned short*>(&o1);
#pragma unroll
        for (int j = 0; j < 8; ++j) {
          s0[j] = f2bf(v2[j].x);
          s1[j] = f2bf(v2[j].y);
        }
        int a0 = col0*128 + (((chunk ^ col0) & 7) << 4);
        int a1 = col1*128 + (((chunk ^ col1) & 7) << 4);
        *reinterpret_cast<uint4*>(ldsrow + a0) = o0;
        *reinterpret_cast<uint4*>(ldsrow + a1) = o1;
      }
    } else {
      uint4 zv; zv.x = 0; zv.y = 0; zv.z = 0; zv.w = 0;
#pragma unroll
      for (int it = 0; it < 17; ++it) {
        int di = it*64 + lane;
        if (di < 1040) *reinterpret_cast<uint4*>(ldsrow + di*16) = zv;
      }
    }
  }
  __syncthreads();

  int l15 = lane & 15, lhi = lane >> 4;
  int phr = v >> 1, pw0 = (v & 1)*64;
  f32x4 acc[4][4];   // [pixel tile][co tile]
#pragma unroll
  for (int mp = 0; mp < 4; ++mp)
#pragma unroll
    for (int nc = 0; nc < 4; ++nc)
      acc[mp][nc] = (f32x4){0.f, 0.f, 0.f, 0.f};

  const unsigned short* wb = wfrag + (size_t)b*(NT*4*64*8);
#pragma unroll
  for (int t = 0; t < NT; ++t) {
    int kk = t >> 1, kh = kk/3, kw = kk%3, half = t & 1;
    short8 wf[4];
#pragma unroll
    for (int nc = 0; nc < 4; ++nc)         // B operand: weights (L2-hot, 1 KiB/instr)
      wf[nc] = *reinterpret_cast<const short8*>(wb + ((t*4 + nc)*64 + lane)*8);
    int chunk = half*4 + lhi;              // ci0>>3
    short8 xa[4];
#pragma unroll
    for (int mp = 0; mp < 4; ++mp) {       // A operand: pixels from LDS
      int col = pw0 + mp*16 + l15 + kw;    // padded col = pix + kw, in [0,129]
      int addr = ((phr + kh)*130 + col)*128 + (((chunk ^ col) & 7) << 4);
      xa[mp] = *reinterpret_cast<const short8*>(&xs[addr]);
    }
#pragma unroll
    for (int mp = 0; mp < 4; ++mp)
#pragma unroll
      for (int nc = 0; nc < 4; ++nc)
        acc[mp][nc] = __builtin_amdgcn_mfma_f32_16x16x32_bf16(xa[mp], wf[nc], acc[mp][nc], 0, 0, 0);
  }

  // ---- epilogue: D row=(lane>>4)*4+i -> pixel (contiguous f32x4), col=lane&15 -> co
  int ph = h0 + phr;
#pragma unroll
  for (int nc = 0; nc < 4; ++nc) {
    int co = nc*16 + l15;
    float* op = out + (((size_t)b*C_ + co)*H_ + ph)*W_;
#pragma unroll
    for (int mp = 0; mp < 4; ++mp) {
      int pix = pw0 + mp*16 + lhi*4;
      *reinterpret_cast<f32x4*>(op + pix) = acc[mp][nc];
    }
  }
}

__global__ void sentinel_k(float* out, int n) {
  int i = blockIdx.x*256 + threadIdx.x;
  if (i < n) out[i] = 1.0e6f;
}

extern "C" void kernel_launch(void* const* d_in, const int* in_sizes, int n_in,
                              void* d_out, int out_size, void* d_ws, size_t ws_size,
                              hipStream_t stream) {
  const float* x  = (const float*)d_in[0];
  const float* z  = (const float*)d_in[1];
  const float* gw = (const float*)d_in[2];
  const float* gb = (const float*)d_in[3];
  float* out = (float*)d_out;

  size_t wfrag_elems = (size_t)B_*IDXN;                   // bf16 elems
  size_t need = wfrag_elems*sizeof(unsigned short);
  if (ws_size < need) {
    sentinel_k<<<(out_size + 255)/256, 256, 0, stream>>>(out, out_size);
    return;
  }
  unsigned short* wfrag = (unsigned short*)d_ws;

  wgen_k <<<IDXN/128, 256, 0, stream>>>(z, gw, gb, wfrag);
  conv_k <<<B_*(H_/2),256, 0, stream>>>(x, wfrag, out);
}